// Round 10
// baseline (339.921 us; speedup 1.0000x reference)
//
#include <hip/hip_runtime.h>
#include <math.h>

typedef _Float16 f16x8 __attribute__((ext_vector_type(8)));
typedef _Float16 f16x4 __attribute__((ext_vector_type(4)));
typedef _Float16 f16x2 __attribute__((ext_vector_type(2)));
typedef float    f32x4 __attribute__((ext_vector_type(4)));

#define FEAT_H 128
#define FEAT_W 352
#define FPIX   (FEAT_H * FEAT_W)   // 45056
#define BEV    320
#define NCELL  (BEV * BEV)         // 102400
#define CH     96
#define PD     322                 // padded spatial dim
#define PPIX   (PD * PD)           // 103684

// ---- workspace layout (float offsets) ----
#define N_PADF    (2 * PPIX * CH / 2)            // 9,953,664 floats
#define OFF_BUFB  0
#define OFF_FS    0                              // featS16: 2*45056*64 f16
#define OFF_FH    2883584                        // featH16: 2*45056*96 f16
#define OFF_WT    (N_PADF)                       // f16 2*9*96*96 = 82,944 floats
#define OFF_HW    (OFF_WT + 82944)               // 64*64 fp32
#define OFF_BASE  (OFF_HW + 4096)                // baseT 192 | wD 64 | flag 1
#define OFF_WD    (OFF_BASE + 192)
#define OFF_FLAG  (OFF_BASE + 256)
#define OFF_BUFA  (OFF_BASE + 512)               // f16 padded conv1 input

// ---------------------------------------------------------------------------
// k_setup (round-15 parallel form, proven in round 9):
//   blocks 0..15   -> hW (1 output/thread, parallel)
//   block  16      -> baseT (192 outputs) + flag
//   blocks 17..664 -> weight prep (fragment order)
//   blocks 665..675-> bufA border zero
// wD (depends on hW) in k_setup2 (stream order = dependency).
// ---------------------------------------------------------------------------
__global__ void k_setup(const float* __restrict__ dw2, const float* __restrict__ sw1,
                        const float* __restrict__ db2, const float* __restrict__ he,
                        const float* __restrict__ sb1, const float* __restrict__ db1,
                        const float* __restrict__ w1, const float* __restrict__ w2,
                        float* __restrict__ hW, float* __restrict__ baseT,
                        float* __restrict__ flagp,
                        _Float16* __restrict__ wt, _Float16* __restrict__ bufA) {
    const int bid = blockIdx.x;
    const int t = threadIdx.x;
    if (bid < 16) {
        const int idx = bid * 256 + t;              // 0..4095
        const int j = idx >> 6, k = idx & 63;
        float s = 0.f;
        for (int c = 0; c < CH; c++) s = fmaf(dw2[j * CH + c], sw1[c * 64 + k], s);
        hW[idx] = s;
    } else if (bid == 16) {
        if (t < 192) {
            const int h = t >> 6, k = t & 63;
            float s = sb1[k];
            for (int c = 0; c < CH; c++) s = fmaf(db2[c] + he[h * CH + c], sw1[c * 64 + k], s);
            baseT[t] = s;
        } else if (t == 192) {
            float mx = 0.f;
            for (int j = 0; j < 64; j++) mx = fmaxf(mx, fabsf(db1[j]));
            flagp[0] = (mx == 0.f) ? 1.f : 0.f;
        }
    } else if (bid <= 664) {
        int idx = (bid - 17) * 256 + t;             // 0 .. 165887
        int cv = idx / 82944; int r = idx - cv * 82944;
        // fragment-order decompose: tap, kc, och, ot, lane, e
        int tap = r / 9216;   int r2 = r - tap * 9216;     // 9216 = 3*2*3*512
        int kc  = r2 / 3072;  int r3 = r2 - kc * 3072;
        int och = r3 / 1536;  int r4 = r3 - och * 1536;
        int ot  = r4 / 512;   int r5 = r4 - ot * 512;
        int l   = r5 >> 3;    int e  = r5 & 7;
        int oc  = och * 48 + ot * 16 + (l & 15);
        int ic  = kc * 32 + (l >> 4) * 8 + e;
        const float* src = cv ? w2 : w1;
        wt[idx] = (_Float16)src[(oc * 96 + ic) * 9 + tap];
    } else {
        int idx = (bid - 665) * 256 + t;            // 0 .. 2815 (need 2568)
        if (idx >= 2568) return;
        int img = idx / 1284; int p = idx - img * 1284;
        int row, col;
        if (p < 322)      { row = 0;           col = p; }
        else if (p < 644) { row = 321;         col = p - 322; }
        else if (p < 964) { row = p - 644 + 1; col = 0; }
        else              { row = p - 964 + 1; col = 321; }
        _Float16* q = bufA + ((size_t)(img * PD + row) * PD + col) * CH;
        f16x8 z = {};
        #pragma unroll
        for (int c8 = 0; c8 < 12; ++c8) *(f16x8*)(q + c8 * 8) = z;
    }
}

// ---------------------------------------------------------------------------
// k_setup2: wD[t] = sum_j relu-gated dw1[j] * hW[j][t]  (after k_setup).
// ---------------------------------------------------------------------------
__global__ __launch_bounds__(64) void k_setup2(const float* __restrict__ dw1,
                                               const float* __restrict__ hW,
                                               float* __restrict__ wD) {
    const int t = threadIdx.x;
    float s = 0.f;
    for (int j = 0; j < 64; j++) {
        float w = dw1[j];
        if (w > 0.f) s = fmaf(w, hW[j * 64 + t], s);
    }
    wD[t] = s;
}

// ---------------------------------------------------------------------------
// Zero the 1-pixel border of a padded f16 HWC buffer [2][322][322][96]
// ---------------------------------------------------------------------------
__global__ void k_border(_Float16* __restrict__ buf) {
    int idx = blockIdx.x * 256 + threadIdx.x;       // 2*1284 = 2568 border pixels
    if (idx >= 2568) return;
    int img = idx / 1284; int p = idx - img * 1284;
    int row, col;
    if (p < 322)      { row = 0;           col = p; }
    else if (p < 644) { row = 321;         col = p - 322; }
    else if (p < 964) { row = p - 644 + 1; col = 0; }
    else              { row = p - 964 + 1; col = 321; }
    _Float16* q = buf + ((size_t)(img * PD + row) * PD + col) * CH;
    f16x8 z = {};
    #pragma unroll
    for (int c8 = 0; c8 < 12; ++c8) *(f16x8*)(q + c8 * 8) = z;
}

// ---------------------------------------------------------------------------
// k_feats (round 16): r5 body + EXPLICIT 3-BUFFER PREFETCH ROTATION
// (the conv kernel's proven xa/xb/xc pattern). Latency-bound at 1408 waves
// (grid cap); only lever left is ILP: ~24 loads in flight instead of ~8,
// cutting dependent stall groups 12 -> ~4-5. Body per step is identical to
// r5 (punctuating featH stores keep codegen sane); live set +16 VGPR.
// ---------------------------------------------------------------------------
#define LOADX(X, G) do {                                                           \
    _Pragma("unroll")                                                              \
    for (int e = 0; e < 8; e++) X[e] = fp[(size_t)((G) * 8 + e) * FPIX];           \
} while (0)

#define PROCX(X, G) do {                                                           \
    f16x8 v;                                                                       \
    _Pragma("unroll")                                                              \
    for (int e = 0; e < 8; e++) v[e] = (_Float16)X[e];                             \
    *(f16x8*)(opH + (G) * 8) = v;                                                  \
    _Pragma("unroll")                                                              \
    for (int e = 0; e < 8; e++) {                                                  \
        const float4* wr = (const float4*)(sw1 + ((G) * 8 + e) * 64);              \
        _Pragma("unroll")                                                          \
        for (int k4 = 0; k4 < 16; k4++) {                                          \
            float4 w = wr[k4];                                                     \
            acc[4 * k4 + 0] = fmaf(X[e], w.x, acc[4 * k4 + 0]);                    \
            acc[4 * k4 + 1] = fmaf(X[e], w.y, acc[4 * k4 + 1]);                    \
            acc[4 * k4 + 2] = fmaf(X[e], w.z, acc[4 * k4 + 2]);                    \
            acc[4 * k4 + 3] = fmaf(X[e], w.w, acc[4 * k4 + 3]);                    \
        }                                                                          \
    }                                                                              \
} while (0)

__global__ __launch_bounds__(64) void k_feats(const float* __restrict__ feat,
                                              const float* __restrict__ sw1,
                                              _Float16* __restrict__ featS,
                                              _Float16* __restrict__ featH) {
    const int t = threadIdx.x;
    const int pb = blockIdx.x * 64;
    const int b = blockIdx.y;
    const float* fp = feat + (size_t)b * CH * FPIX + pb + t;
    _Float16* opH = featH + ((size_t)b * FPIX + pb + t) * 96;

    float acc[64];
    #pragma unroll
    for (int k = 0; k < 64; k++) acc[k] = 0.f;

    float xa[8], xb[8], xc[8];
    LOADX(xa, 0); LOADX(xb, 1);
    LOADX(xc, 2);  PROCX(xa, 0);
    LOADX(xa, 3);  PROCX(xb, 1);
    LOADX(xb, 4);  PROCX(xc, 2);
    LOADX(xc, 5);  PROCX(xa, 3);
    LOADX(xa, 6);  PROCX(xb, 4);
    LOADX(xb, 7);  PROCX(xc, 5);
    LOADX(xc, 8);  PROCX(xa, 6);
    LOADX(xa, 9);  PROCX(xb, 7);
    LOADX(xb, 10); PROCX(xc, 8);
    LOADX(xc, 11); PROCX(xa, 9);
    PROCX(xb, 10);
    PROCX(xc, 11);

    _Float16* opS = featS + ((size_t)b * FPIX + pb + t) * 64;
    #pragma unroll
    for (int k8 = 0; k8 < 8; k8++) {
        f16x8 v;
        #pragma unroll
        for (int e = 0; e < 8; e++) v[e] = (_Float16)acc[k8 * 8 + e];
        *(f16x8*)(opS + k8 * 8) = v;
    }
}

// ---------------------------------------------------------------------------
// k_lift: cooperative 16-lane-per-cell gather. (unchanged, proven)
// ---------------------------------------------------------------------------
__global__ __launch_bounds__(256, 4) void k_lift(const _Float16* __restrict__ featS,
                                                 const _Float16* __restrict__ featH,
                                                 const float* __restrict__ l2i,
                                                 const float* __restrict__ dw1,
                                                 const float* __restrict__ db1,
                                                 const float* __restrict__ sw2,
                                                 const float* __restrict__ sb2,
                                                 const float* __restrict__ hW,
                                                 const float* __restrict__ baseT,
                                                 const float* __restrict__ wD,
                                                 const float* __restrict__ flagp,
                                                 _Float16* __restrict__ out) {
    const int tid = threadIdx.x;
    const int g = tid >> 4;                 // group (cell) within block: 0..15
    const int r = tid & 15;                 // lane within group: 0..15
    const int b = blockIdx.y;
    const int cell = blockIdx.x * 16 + g;
    const int i = cell / BEV, j = cell % BEV;
    const float px = ((j + 0.5f) / 320.0f) * 102.4f - 51.2f;
    const float py = ((i + 0.5f) / 320.0f) * 102.4f - 51.2f;
    const float* M = l2i + b * 16;
    const float m00 = M[0], m01 = M[1], m02 = M[2], m03 = M[3];
    const float m10 = M[4], m11 = M[5], m12 = M[6], m13 = M[7];
    const float m20 = M[8], m21 = M[9], m22 = M[10], m23 = M[11];

    const _Float16* fSb = featS + (size_t)b * FPIX * 64;
    const _Float16* fHb = featH + (size_t)b * FPIX * 96;

    // per-lane channel slices of the small tables
    const f32x4 wdv = *(const f32x4*)(wD + r * 4);
    const f32x4 sv  = *(const f32x4*)(sw2 + r * 4);
    const float sb2v = sb2[0];
    const bool fast = (flagp[0] != 0.f);

    int   ti[3][4];
    float tw[3][4];
    float logit[3];

    #pragma unroll
    for (int h = 0; h < 3; h++) {
        logit[h] = -INFINITY;
        ti[h][0] = ti[h][1] = ti[h][2] = ti[h][3] = 0;
        tw[h][0] = tw[h][1] = tw[h][2] = tw[h][3] = 0.f;
        const float z = (float)h;
        const float p0 = m03 + m00 * px + m01 * py + m02 * z;
        const float p1 = m13 + m10 * px + m11 * py + m12 * z;
        const float dep = m23 + m20 * px + m21 * py + m22 * z;
        const float dv = fmaxf(dep, 1e-5f);
        const float u = p0 / dv, v = p1 / dv;
        const float gx = (u / 351.0f) * 2.0f - 1.0f;
        const float gy = (v / 127.0f) * 2.0f - 1.0f;
        const bool valid = (dep > 1e-3f) && (fabsf(gx) <= 1.0f) && (fabsf(gy) <= 1.0f);
        if (!valid) continue;                       // group-uniform branch

        float xs = (gx + 1.0f) * 0.5f * 351.0f;
        float ys = (gy + 1.0f) * 0.5f * 127.0f;
        float xf = floorf(xs), yf = floorf(ys);
        int x0 = (int)xf, y0 = (int)yf;
        float wx = xs - xf, wy = ys - yf;
        int x1 = (x0 < FEAT_W - 1) ? x0 + 1 : x0;
        int y1 = (y0 < FEAT_H - 1) ? y0 + 1 : y0;
        ti[h][0] = y0 * FEAT_W + x0;  ti[h][1] = y0 * FEAT_W + x1;
        ti[h][2] = y1 * FEAT_W + x0;  ti[h][3] = y1 * FEAT_W + x1;
        const float tw0 = (1.f - wx) * (1.f - wy), tw1 = wx * (1.f - wy);
        const float tw2 = (1.f - wx) * wy,         tw3 = wx * wy;
        tw[h][0] = tw0; tw[h][1] = tw1; tw[h][2] = tw2; tw[h][3] = tw3;

        const float dl = log1pf(fmaxf(dep, 1e-3f));

        // coalesced featS taps: 16 lanes x 8B = one 128B line per tap
        f16x4 t0 = *(const f16x4*)(fSb + (size_t)ti[h][0] * 64 + r * 4);
        f16x4 t1 = *(const f16x4*)(fSb + (size_t)ti[h][1] * 64 + r * 4);
        f16x4 t2 = *(const f16x4*)(fSb + (size_t)ti[h][2] * 64 + r * 4);
        f16x4 t3 = *(const f16x4*)(fSb + (size_t)ti[h][3] * 64 + r * 4);
        const f32x4 bs = *(const f32x4*)(baseT + h * 64 + r * 4);

        float hid[4];
        if (fast) {
            #pragma unroll
            for (int k = 0; k < 4; k++) hid[k] = fmaf(dl, wdv[k], bs[k]);
        } else {
            #pragma unroll
            for (int k = 0; k < 4; k++) hid[k] = bs[k];
            for (int jj = 0; jj < 64; jj++) {
                float hd = fmaxf(fmaf(dl, dw1[jj], db1[jj]), 0.f);
                const f32x4 hv = *(const f32x4*)(hW + jj * 64 + r * 4);
                #pragma unroll
                for (int k = 0; k < 4; k++) hid[k] = fmaf(hd, hv[k], hid[k]);
            }
        }
        float part = 0.f;
        #pragma unroll
        for (int k = 0; k < 4; k++) {
            float s = fmaf(tw0, (float)t0[k], fmaf(tw1, (float)t1[k],
                      fmaf(tw2, (float)t2[k], tw3 * (float)t3[k])));
            part = fmaf(fmaxf(hid[k] + s, 0.f), sv[k], part);
        }
        // butterfly reduce across the 16-lane group
        #pragma unroll
        for (int m = 1; m < 16; m <<= 1) part += __shfl_xor(part, m, 16);
        logit[h] = part + sb2v;
    }

    const float mx = fmaxf(logit[0], fmaxf(logit[1], logit[2]));
    float wh[3] = {0.f, 0.f, 0.f};
    if (mx > -INFINITY) {
        float e0 = (logit[0] > -INFINITY) ? expf(logit[0] - mx) : 0.f;
        float e1 = (logit[1] > -INFINITY) ? expf(logit[1] - mx) : 0.f;
        float e2 = (logit[2] > -INFINITY) ? expf(logit[2] - mx) : 0.f;
        const float inv = 1.0f / (e0 + e1 + e2);
        wh[0] = e0 * inv; wh[1] = e1 * inv; wh[2] = e2 * inv;
    }

    // fused 96-ch weighted gather: lane r owns ch [4r..4r+3] and [64+2r..64+2r+1]
    float acc4[4] = {0.f, 0.f, 0.f, 0.f};
    float acc2[2] = {0.f, 0.f};
    #pragma unroll
    for (int h = 0; h < 3; h++) {
        if (wh[h] > 0.f) {                          // group-uniform branch
            #pragma unroll
            for (int t = 0; t < 4; t++) {
                const float c = wh[h] * tw[h][t];
                const _Float16* gp = fHb + (size_t)ti[h][t] * 96;
                f16x4 v4 = *(const f16x4*)(gp + r * 4);
                f16x2 v2 = *(const f16x2*)(gp + 64 + r * 2);
                #pragma unroll
                for (int k = 0; k < 4; k++) acc4[k] = fmaf(c, (float)v4[k], acc4[k]);
                acc2[0] = fmaf(c, (float)v2[0], acc2[0]);
                acc2[1] = fmaf(c, (float)v2[1], acc2[1]);
            }
        }
    }
    _Float16* op = out + ((size_t)(b * PD + i + 1) * PD + (j + 1)) * CH;
    f16x4 s4;
    #pragma unroll
    for (int k = 0; k < 4; k++) s4[k] = (_Float16)acc4[k];
    *(f16x4*)(op + r * 4) = s4;
    f16x2 s2;
    s2[0] = (_Float16)acc2[0];
    s2[1] = (_Float16)acc2[1];
    *(f16x2*)(op + 64 + r * 2) = s2;
}

// ---------------------------------------------------------------------------
// Conv 3x3 + BN + ReLU, f16 MFMA implicit GEMM. (unchanged, round-11 proven:
// 512 thr, 8 waves, 10x34 pixel-major LDS, depth-1 SAB/SBA, grid 800 + XCD
// swizzle, FRAGMENT-ORDER weights)
// ---------------------------------------------------------------------------
#define LOAD_FRAGS(WF, PF, STEP) do {                                              \
    constexpr int _tap = (STEP) / 3, _kc = (STEP) % 3;                             \
    constexpr int _r = _tap / 3, _s = _tap % 3;                                    \
    _Pragma("unroll")                                                              \
    for (int ot = 0; ot < 3; ++ot)                                                 \
        WF[ot] = *(const f16x8*)(wtb + _tap * 9216 + _kc * 3072 + ot * 512);       \
    _Pragma("unroll")                                                              \
    for (int pt = 0; pt < 4; ++pt)                                                 \
        PF[pt] = *(const f16x8*)(&sA[((2 * rp + (pt >> 1) + _r) * 34               \
                         + (pt & 1) * 16 + _s + n) * 104 + _kc * 32 + q * 8]);     \
} while (0)

#define DO_MFMA(WF, PF) do {                                                       \
    _Pragma("unroll")                                                              \
    for (int ot = 0; ot < 3; ++ot)                                                 \
        _Pragma("unroll")                                                          \
        for (int pt = 0; pt < 4; ++pt)                                             \
            acc[ot][pt] = __builtin_amdgcn_mfma_f32_16x16x32_f16(                  \
                              WF[ot], PF[pt], acc[ot][pt], 0, 0, 0);               \
} while (0)

#define SAB(S) LOAD_FRAGS(wfb, pfb, (S) + 1); DO_MFMA(wfa, pfa);
#define SBA(S) LOAD_FRAGS(wfa, pfa, (S) + 1); DO_MFMA(wfb, pfb);

template<int MODE>
__global__ __launch_bounds__(512, 4) void k_conv_mfma(
        const _Float16* __restrict__ in, const _Float16* __restrict__ wt,
        const float* __restrict__ bng, const float* __restrict__ bnb,
        const float* __restrict__ bnm, const float* __restrict__ bnv,
        void* __restrict__ outv) {
    __shared__ _Float16 sA[10 * 34 * 104];   // 70,720 B -> 2 blocks/CU
    const int tid = threadIdx.x;
    const int w = tid >> 6, lane = tid & 63, q = lane >> 4, n = lane & 15;
    const int rp = w >> 1;          // row-pair 0..3
    const int och = w & 1;          // oc half 0..1

    // bijective XCD swizzle: 800 % 8 == 0
    const int bid = blockIdx.x;
    const int swz = (bid & 7) * 100 + (bid >> 3);
    const int b = swz / 400;
    const int r2 = swz - b * 400;
    const int ty = r2 / 10, tx = r2 - ty * 10;
    const int x0 = tx * 32, y0 = ty * 8;

    const _Float16* inb = in + (size_t)b * PPIX * CH;

    for (int idx = tid; idx < 10 * 34 * 12; idx += 512) {
        int pix = idx / 12, c8 = idx - pix * 12;
        int rr = pix / 34, cc = pix - rr * 34;
        *(f16x8*)(&sA[pix * 104 + c8 * 8]) =
            *(const f16x8*)(inb + ((size_t)(y0 + rr) * PD + (x0 + cc)) * CH + c8 * 8);
    }
    __syncthreads();

    f32x4 acc[3][4];
    #pragma unroll
    for (int ot = 0; ot < 3; ot++)
        #pragma unroll
        for (int pt = 0; pt < 4; pt++) acc[ot][pt] = (f32x4){0.f, 0.f, 0.f, 0.f};

    // fragment-order weights: + och half, + per-lane 16B slot
    const _Float16* wtb = wt + och * 1536 + lane * 8;

    f16x8 wfa[3], wfb[3], pfa[4], pfb[4];
    LOAD_FRAGS(wfa, pfa, 0);
    SAB(0)  SBA(1)  SAB(2)  SBA(3)  SAB(4)  SBA(5)  SAB(6)  SBA(7)
    SAB(8)  SBA(9)  SAB(10) SBA(11) SAB(12) SBA(13) SAB(14) SBA(15)
    SAB(16) SBA(17) SAB(18) SBA(19) SAB(20) SBA(21) SAB(22) SBA(23)
    SAB(24) SBA(25)
    DO_MFMA(wfa, pfa);   // step 26 (loaded by SBA(25))

    float scv[3][4], shv[3][4];
    #pragma unroll
    for (int ot = 0; ot < 3; ot++)
        #pragma unroll
        for (int rg = 0; rg < 4; rg++) {
            int oc = och * 48 + ot * 16 + q * 4 + rg;
            scv[ot][rg] = bng[oc] * rsqrtf(bnv[oc] + 1e-3f);
            shv[ot][rg] = fmaf(-bnm[oc], scv[ot][rg], bnb[oc]);
        }

    if (MODE == 0) {
        _Float16* outb = (_Float16*)outv + (size_t)b * PPIX * CH;
        #pragma unroll
        for (int pt = 0; pt < 4; pt++) {
            const int orow = y0 + 2 * rp + (pt >> 1) + 1;
            const int ocol = x0 + (pt & 1) * 16 + n + 1;
            _Float16* op = outb + ((size_t)orow * PD + ocol) * CH + och * 48 + q * 4;
            #pragma unroll
            for (int ot = 0; ot < 3; ot++) {
                f16x4 pv;
                #pragma unroll
                for (int rg = 0; rg < 4; rg++)
                    pv[rg] = (_Float16)fmaxf(fmaf(acc[ot][pt][rg], scv[ot][rg], shv[ot][rg]), 0.f);
                *(f16x4*)(op + ot * 16) = pv;
            }
        }
    } else {
        float* outb = (float*)outv + (size_t)b * CH * NCELL;
        #pragma unroll
        for (int pt = 0; pt < 4; pt++) {
            const int prow = y0 + 2 * rp + (pt >> 1);
            const int pcol = x0 + (pt & 1) * 16 + n;
            #pragma unroll
            for (int ot = 0; ot < 3; ot++)
                #pragma unroll
                for (int rg = 0; rg < 4; rg++) {
                    int oc = och * 48 + ot * 16 + q * 4 + rg;
                    outb[(size_t)oc * NCELL + prow * BEV + pcol] =
                        fmaxf(fmaf(acc[ot][pt][rg], scv[ot][rg], shv[ot][rg]), 0.f);
                }
        }
    }
}

// ---------------------------------------------------------------------------
extern "C" void kernel_launch(void* const* d_in, const int* in_sizes, int n_in,
                              void* d_out, int out_size, void* d_ws, size_t ws_size,
                              hipStream_t stream) {
    const float* feat = (const float*)d_in[0];
    const float* l2i  = (const float*)d_in[1];
    const float* he   = (const float*)d_in[2];
    const float* dw1  = (const float*)d_in[3];
    const float* db1  = (const float*)d_in[4];
    const float* dw2  = (const float*)d_in[5];
    const float* db2  = (const float*)d_in[6];
    const float* sw1  = (const float*)d_in[7];
    const float* sb1  = (const float*)d_in[8];
    const float* sw2  = (const float*)d_in[9];
    const float* sb2  = (const float*)d_in[10];
    const float* c1w  = (const float*)d_in[11];
    const float* bn1g = (const float*)d_in[12];
    const float* bn1b = (const float*)d_in[13];
    const float* bn1m = (const float*)d_in[14];
    const float* bn1v = (const float*)d_in[15];
    const float* c2w  = (const float*)d_in[16];
    const float* bn2g = (const float*)d_in[17];
    const float* bn2b = (const float*)d_in[18];
    const float* bn2m = (const float*)d_in[19];
    const float* bn2v = (const float*)d_in[20];

    float* ws = (float*)d_ws;
    _Float16*  bufB   = (_Float16*)(ws + OFF_BUFB);
    _Float16*  featS  = (_Float16*)(ws + OFF_FS);   // aliases bufB (dead before conv1)
    _Float16*  featH  = (_Float16*)(ws + OFF_FH);   // aliases bufB (dead before conv1)
    _Float16*  wtp    = (_Float16*)(ws + OFF_WT);
    float*     hW     = ws + OFF_HW;
    float*     baseT  = ws + OFF_BASE;
    float*     wD     = ws + OFF_WD;
    float*     flagp  = ws + OFF_FLAG;
    _Float16*  bufA   = (_Float16*)(ws + OFF_BUFA);
    _Float16*  wt1    = wtp;
    _Float16*  wt2    = wtp + 82944;

    hipLaunchKernelGGL(k_setup, dim3(676), dim3(256), 0, stream,
                       dw2, sw1, db2, he, sb1, db1, c1w, c2w,
                       hW, baseT, flagp, wtp, bufA);
    hipLaunchKernelGGL(k_setup2, dim3(1), dim3(64), 0, stream, dw1, hW, wD);
    hipLaunchKernelGGL(k_feats, dim3(FPIX / 64, 2), dim3(64), 0, stream,
                       feat, sw1, featS, featH);
    hipLaunchKernelGGL(k_lift, dim3(NCELL / 16, 2), dim3(256), 0, stream,
                       featS, featH, l2i, dw1, db1, sw2, sb2, hW, baseT, wD, flagp, bufA);
    // bufB borders only after k_lift (featS/featH alias bufB)
    hipLaunchKernelGGL(k_border, dim3(11), dim3(256), 0, stream, bufB);
    hipLaunchKernelGGL((k_conv_mfma<0>), dim3(800), dim3(512), 0, stream,
                       bufA, wt1, bn1g, bn1b, bn1m, bn1v, (void*)bufB);
    hipLaunchKernelGGL((k_conv_mfma<1>), dim3(800), dim3(512), 0, stream,
                       bufB, wt2, bn2g, bn2b, bn2m, bn2v, d_out);
}

// Round 12
// 308.044 us; speedup vs baseline: 1.1035x; 1.1035x over previous
//
#include <hip/hip_runtime.h>
#include <math.h>

typedef _Float16 f16x8 __attribute__((ext_vector_type(8)));
typedef _Float16 f16x4 __attribute__((ext_vector_type(4)));
typedef _Float16 f16x2 __attribute__((ext_vector_type(2)));
typedef float    f32x4 __attribute__((ext_vector_type(4)));

#define FEAT_H 128
#define FEAT_W 352
#define FPIX   (FEAT_H * FEAT_W)   // 45056
#define BEV    320
#define NCELL  (BEV * BEV)         // 102400
#define CH     96
#define PD     322                 // padded spatial dim
#define PPIX   (PD * PD)           // 103684

// ---- workspace layout (float offsets) ----
#define N_PADF    (2 * PPIX * CH / 2)            // 9,953,664 floats
#define OFF_BUFB  0
#define OFF_FS    0                              // featS16: 2*45056*64 f16
#define OFF_FH    2883584                        // featH16: 2*45056*96 f16
#define OFF_WT    (N_PADF)                       // f16 2*9*96*96 = 82,944 floats
#define OFF_HW    (OFF_WT + 82944)               // 64*64 fp32
#define OFF_BASE  (OFF_HW + 4096)                // baseT 192 | wD 64 | flag 1
#define OFF_WD    (OFF_BASE + 192)
#define OFF_FLAG  (OFF_BASE + 256)
#define OFF_SW1H  (OFF_BASE + 512)               // sw1 fragment-order f16: 6144 f16 = 3072 floats
#define OFF_BUFA  (OFF_SW1H + 3072)              // f16 padded conv1 input

// ---------------------------------------------------------------------------
// k_setup (round 17, resubmitted after infra failure):
//   blocks 0..15   -> hW (1 output/thread, parallel)
//   block  16      -> baseT (192 outputs) + flag
//   blocks 17..40  -> sw1p: sw1 in MFMA B-FRAGMENT order [kc][nt][lane][8]
//   blocks 41..688 -> conv weight prep (fragment order)
//   blocks 689..699-> bufA border zero
// wD (depends on hW) in k_setup2 (stream order = dependency).
// ---------------------------------------------------------------------------
__global__ void k_setup(const float* __restrict__ dw2, const float* __restrict__ sw1,
                        const float* __restrict__ db2, const float* __restrict__ he,
                        const float* __restrict__ sb1, const float* __restrict__ db1,
                        const float* __restrict__ w1, const float* __restrict__ w2,
                        float* __restrict__ hW, float* __restrict__ baseT,
                        float* __restrict__ flagp, _Float16* __restrict__ sw1p,
                        _Float16* __restrict__ wt, _Float16* __restrict__ bufA) {
    const int bid = blockIdx.x;
    const int t = threadIdx.x;
    if (bid < 16) {
        const int idx = bid * 256 + t;              // 0..4095
        const int j = idx >> 6, k = idx & 63;
        float s = 0.f;
        for (int c = 0; c < CH; c++) s = fmaf(dw2[j * CH + c], sw1[c * 64 + k], s);
        hW[idx] = s;
    } else if (bid == 16) {
        if (t < 192) {
            const int h = t >> 6, k = t & 63;
            float s = sb1[k];
            for (int c = 0; c < CH; c++) s = fmaf(db2[c] + he[h * CH + c], sw1[c * 64 + k], s);
            baseT[t] = s;
        } else if (t == 192) {
            float mx = 0.f;
            for (int j = 0; j < 64; j++) mx = fmaxf(mx, fabsf(db1[j]));
            flagp[0] = (mx == 0.f) ? 1.f : 0.f;
        }
    } else if (bid <= 40) {
        const int idx = (bid - 17) * 256 + t;       // 0..6143
        const int e  = idx & 7;
        const int l  = (idx >> 3) & 63;
        const int nt = (idx >> 9) & 3;
        const int kc = idx >> 11;                   // 0..2
        const int q = l >> 4, n = l & 15;
        sw1p[idx] = (_Float16)sw1[(kc * 32 + q * 8 + e) * 64 + nt * 16 + n];
    } else if (bid <= 688) {
        int idx = (bid - 41) * 256 + t;             // 0 .. 165887
        int cv = idx / 82944; int r = idx - cv * 82944;
        // fragment-order decompose: tap, kc, och, ot, lane, e
        int tap = r / 9216;   int r2 = r - tap * 9216;     // 9216 = 3*2*3*512
        int kc  = r2 / 3072;  int r3 = r2 - kc * 3072;
        int och = r3 / 1536;  int r4 = r3 - och * 1536;
        int ot  = r4 / 512;   int r5 = r4 - ot * 512;
        int l   = r5 >> 3;    int e  = r5 & 7;
        int oc  = och * 48 + ot * 16 + (l & 15);
        int ic  = kc * 32 + (l >> 4) * 8 + e;
        const float* src = cv ? w2 : w1;
        wt[idx] = (_Float16)src[(oc * 96 + ic) * 9 + tap];
    } else {
        int idx = (bid - 689) * 256 + t;            // 0 .. 2815 (need 2568)
        if (idx >= 2568) return;
        int img = idx / 1284; int p = idx - img * 1284;
        int row, col;
        if (p < 322)      { row = 0;           col = p; }
        else if (p < 644) { row = 321;         col = p - 322; }
        else if (p < 964) { row = p - 644 + 1; col = 0; }
        else              { row = p - 964 + 1; col = 321; }
        _Float16* q = bufA + ((size_t)(img * PD + row) * PD + col) * CH;
        f16x8 z = {};
        #pragma unroll
        for (int c8 = 0; c8 < 12; ++c8) *(f16x8*)(q + c8 * 8) = z;
    }
}

// ---------------------------------------------------------------------------
// k_setup2: wD[t] = sum_j relu-gated dw1[j] * hW[j][t]  (after k_setup).
// ---------------------------------------------------------------------------
__global__ __launch_bounds__(64) void k_setup2(const float* __restrict__ dw1,
                                               const float* __restrict__ hW,
                                               float* __restrict__ wD) {
    const int t = threadIdx.x;
    float s = 0.f;
    for (int j = 0; j < 64; j++) {
        float w = dw1[j];
        if (w > 0.f) s = fmaf(w, hW[j * 64 + t], s);
    }
    wD[t] = s;
}

// ---------------------------------------------------------------------------
// Zero the 1-pixel border of a padded f16 HWC buffer [2][322][322][96]
// ---------------------------------------------------------------------------
__global__ void k_border(_Float16* __restrict__ buf) {
    int idx = blockIdx.x * 256 + threadIdx.x;       // 2*1284 = 2568 border pixels
    if (idx >= 2568) return;
    int img = idx / 1284; int p = idx - img * 1284;
    int row, col;
    if (p < 322)      { row = 0;           col = p; }
    else if (p < 644) { row = 321;         col = p - 322; }
    else if (p < 964) { row = p - 644 + 1; col = 0; }
    else              { row = p - 964 + 1; col = 321; }
    _Float16* q = buf + ((size_t)(img * PD + row) * PD + col) * CH;
    f16x8 z = {};
    #pragma unroll
    for (int c8 = 0; c8 < 12; ++c8) *(f16x8*)(q + c8 * 8) = z;
}

// ---------------------------------------------------------------------------
// k_tr: pure streaming CHW->HWC transpose (feat f32 -> featH f16).
// 256 thr = 4 waves over the same 64 pixels; wave kq owns channels
// [24kq, 24kq+24). 24 independent coalesced 256B loads, 3 f16x8 stores,
// NO accumulator state. 5632 waves, VGPR ~40.
// ---------------------------------------------------------------------------
__global__ __launch_bounds__(256) void k_tr(const float* __restrict__ feat,
                                            _Float16* __restrict__ featH) {
    const int tid = threadIdx.x;
    const int kq = tid >> 6;                // channel quarter 0..3
    const int t = tid & 63;                 // pixel lane
    const int pb = blockIdx.x * 64;
    const int b = blockIdx.y;
    const float* fp = feat + (size_t)b * CH * FPIX + (size_t)(kq * 24) * FPIX + pb + t;
    _Float16* opH = featH + ((size_t)b * FPIX + pb + t) * 96 + kq * 24;

    float x[24];
    #pragma unroll
    for (int c = 0; c < 24; c++) x[c] = fp[(size_t)c * FPIX];
    #pragma unroll
    for (int c8 = 0; c8 < 3; c8++) {
        f16x8 v;
        #pragma unroll
        for (int e = 0; e < 8; e++) v[e] = (_Float16)x[c8 * 8 + e];
        *(f16x8*)(opH + c8 * 8) = v;
    }
}

// ---------------------------------------------------------------------------
// k_fs: featS = featH @ sw1 as an f16 MFMA GEMM.
// [90112 x 96] @ [96 x 64], one 16-row M-tile per wave, 5632 tiles =
// 704 blocks x 8 waves exactly. Fragment math mirrors the verified conv
// kernel: A i=lane&15 k=(lane>>4)*8+e; B j=lane&15 k=(lane>>4)*8+e (via
// sw1p prepack); C col=lane&15 row=(lane>>4)*4+reg.
// ---------------------------------------------------------------------------
__global__ __launch_bounds__(512, 2) void k_fs(const _Float16* __restrict__ featH,
                                               const _Float16* __restrict__ sw1p,
                                               _Float16* __restrict__ featS) {
    const int tid = threadIdx.x;
    const int wid = tid >> 6, lane = tid & 63;
    const int q = lane >> 4, n = lane & 15;
    const int mt = blockIdx.x * 8 + wid;    // 0..5631

    f16x8 bf[3][4];
    #pragma unroll
    for (int kc = 0; kc < 3; kc++)
        #pragma unroll
        for (int nt = 0; nt < 4; nt++)
            bf[kc][nt] = *(const f16x8*)(sw1p + ((kc * 4 + nt) * 64 + lane) * 8);

    f16x8 a[3];
    const _Float16* ar = featH + (size_t)(mt * 16 + n) * 96 + q * 8;
    #pragma unroll
    for (int kc = 0; kc < 3; kc++) a[kc] = *(const f16x8*)(ar + kc * 32);

    f32x4 acc[4];
    #pragma unroll
    for (int nt = 0; nt < 4; nt++) acc[nt] = (f32x4){0.f, 0.f, 0.f, 0.f};
    #pragma unroll
    for (int kc = 0; kc < 3; kc++)
        #pragma unroll
        for (int nt = 0; nt < 4; nt++)
            acc[nt] = __builtin_amdgcn_mfma_f32_16x16x32_f16(a[kc], bf[kc][nt], acc[nt], 0, 0, 0);

    _Float16* os = featS + (size_t)(mt * 16 + q * 4) * 64 + n;
    #pragma unroll
    for (int nt = 0; nt < 4; nt++)
        #pragma unroll
        for (int rg = 0; rg < 4; rg++)
            os[(size_t)rg * 64 + nt * 16] = (_Float16)acc[nt][rg];
}

// ---------------------------------------------------------------------------
// k_lift: cooperative 16-lane-per-cell gather. (unchanged, proven)
// ---------------------------------------------------------------------------
__global__ __launch_bounds__(256, 4) void k_lift(const _Float16* __restrict__ featS,
                                                 const _Float16* __restrict__ featH,
                                                 const float* __restrict__ l2i,
                                                 const float* __restrict__ dw1,
                                                 const float* __restrict__ db1,
                                                 const float* __restrict__ sw2,
                                                 const float* __restrict__ sb2,
                                                 const float* __restrict__ hW,
                                                 const float* __restrict__ baseT,
                                                 const float* __restrict__ wD,
                                                 const float* __restrict__ flagp,
                                                 _Float16* __restrict__ out) {
    const int tid = threadIdx.x;
    const int g = tid >> 4;                 // group (cell) within block: 0..15
    const int r = tid & 15;                 // lane within group: 0..15
    const int b = blockIdx.y;
    const int cell = blockIdx.x * 16 + g;
    const int i = cell / BEV, j = cell % BEV;
    const float px = ((j + 0.5f) / 320.0f) * 102.4f - 51.2f;
    const float py = ((i + 0.5f) / 320.0f) * 102.4f - 51.2f;
    const float* M = l2i + b * 16;
    const float m00 = M[0], m01 = M[1], m02 = M[2], m03 = M[3];
    const float m10 = M[4], m11 = M[5], m12 = M[6], m13 = M[7];
    const float m20 = M[8], m21 = M[9], m22 = M[10], m23 = M[11];

    const _Float16* fSb = featS + (size_t)b * FPIX * 64;
    const _Float16* fHb = featH + (size_t)b * FPIX * 96;

    // per-lane channel slices of the small tables
    const f32x4 wdv = *(const f32x4*)(wD + r * 4);
    const f32x4 sv  = *(const f32x4*)(sw2 + r * 4);
    const float sb2v = sb2[0];
    const bool fast = (flagp[0] != 0.f);

    int   ti[3][4];
    float tw[3][4];
    float logit[3];

    #pragma unroll
    for (int h = 0; h < 3; h++) {
        logit[h] = -INFINITY;
        ti[h][0] = ti[h][1] = ti[h][2] = ti[h][3] = 0;
        tw[h][0] = tw[h][1] = tw[h][2] = tw[h][3] = 0.f;
        const float z = (float)h;
        const float p0 = m03 + m00 * px + m01 * py + m02 * z;
        const float p1 = m13 + m10 * px + m11 * py + m12 * z;
        const float dep = m23 + m20 * px + m21 * py + m22 * z;
        const float dv = fmaxf(dep, 1e-5f);
        const float u = p0 / dv, v = p1 / dv;
        const float gx = (u / 351.0f) * 2.0f - 1.0f;
        const float gy = (v / 127.0f) * 2.0f - 1.0f;
        const bool valid = (dep > 1e-3f) && (fabsf(gx) <= 1.0f) && (fabsf(gy) <= 1.0f);
        if (!valid) continue;                       // group-uniform branch

        float xs = (gx + 1.0f) * 0.5f * 351.0f;
        float ys = (gy + 1.0f) * 0.5f * 127.0f;
        float xf = floorf(xs), yf = floorf(ys);
        int x0 = (int)xf, y0 = (int)yf;
        float wx = xs - xf, wy = ys - yf;
        int x1 = (x0 < FEAT_W - 1) ? x0 + 1 : x0;
        int y1 = (y0 < FEAT_H - 1) ? y0 + 1 : y0;
        ti[h][0] = y0 * FEAT_W + x0;  ti[h][1] = y0 * FEAT_W + x1;
        ti[h][2] = y1 * FEAT_W + x0;  ti[h][3] = y1 * FEAT_W + x1;
        const float tw0 = (1.f - wx) * (1.f - wy), tw1 = wx * (1.f - wy);
        const float tw2 = (1.f - wx) * wy,         tw3 = wx * wy;
        tw[h][0] = tw0; tw[h][1] = tw1; tw[h][2] = tw2; tw[h][3] = tw3;

        const float dl = log1pf(fmaxf(dep, 1e-3f));

        // coalesced featS taps: 16 lanes x 8B = one 128B line per tap
        f16x4 t0 = *(const f16x4*)(fSb + (size_t)ti[h][0] * 64 + r * 4);
        f16x4 t1 = *(const f16x4*)(fSb + (size_t)ti[h][1] * 64 + r * 4);
        f16x4 t2 = *(const f16x4*)(fSb + (size_t)ti[h][2] * 64 + r * 4);
        f16x4 t3 = *(const f16x4*)(fSb + (size_t)ti[h][3] * 64 + r * 4);
        const f32x4 bs = *(const f32x4*)(baseT + h * 64 + r * 4);

        float hid[4];
        if (fast) {
            #pragma unroll
            for (int k = 0; k < 4; k++) hid[k] = fmaf(dl, wdv[k], bs[k]);
        } else {
            #pragma unroll
            for (int k = 0; k < 4; k++) hid[k] = bs[k];
            for (int jj = 0; jj < 64; jj++) {
                float hd = fmaxf(fmaf(dl, dw1[jj], db1[jj]), 0.f);
                const f32x4 hv = *(const f32x4*)(hW + jj * 64 + r * 4);
                #pragma unroll
                for (int k = 0; k < 4; k++) hid[k] = fmaf(hd, hv[k], hid[k]);
            }
        }
        float part = 0.f;
        #pragma unroll
        for (int k = 0; k < 4; k++) {
            float s = fmaf(tw0, (float)t0[k], fmaf(tw1, (float)t1[k],
                      fmaf(tw2, (float)t2[k], tw3 * (float)t3[k])));
            part = fmaf(fmaxf(hid[k] + s, 0.f), sv[k], part);
        }
        // butterfly reduce across the 16-lane group
        #pragma unroll
        for (int m = 1; m < 16; m <<= 1) part += __shfl_xor(part, m, 16);
        logit[h] = part + sb2v;
    }

    const float mx = fmaxf(logit[0], fmaxf(logit[1], logit[2]));
    float wh[3] = {0.f, 0.f, 0.f};
    if (mx > -INFINITY) {
        float e0 = (logit[0] > -INFINITY) ? expf(logit[0] - mx) : 0.f;
        float e1 = (logit[1] > -INFINITY) ? expf(logit[1] - mx) : 0.f;
        float e2 = (logit[2] > -INFINITY) ? expf(logit[2] - mx) : 0.f;
        const float inv = 1.0f / (e0 + e1 + e2);
        wh[0] = e0 * inv; wh[1] = e1 * inv; wh[2] = e2 * inv;
    }

    // fused 96-ch weighted gather: lane r owns ch [4r..4r+3] and [64+2r..64+2r+1]
    float acc4[4] = {0.f, 0.f, 0.f, 0.f};
    float acc2[2] = {0.f, 0.f};
    #pragma unroll
    for (int h = 0; h < 3; h++) {
        if (wh[h] > 0.f) {                          // group-uniform branch
            #pragma unroll
            for (int t = 0; t < 4; t++) {
                const float c = wh[h] * tw[h][t];
                const _Float16* gp = fHb + (size_t)ti[h][t] * 96;
                f16x4 v4 = *(const f16x4*)(gp + r * 4);
                f16x2 v2 = *(const f16x2*)(gp + 64 + r * 2);
                #pragma unroll
                for (int k = 0; k < 4; k++) acc4[k] = fmaf(c, (float)v4[k], acc4[k]);
                acc2[0] = fmaf(c, (float)v2[0], acc2[0]);
                acc2[1] = fmaf(c, (float)v2[1], acc2[1]);
            }
        }
    }
    _Float16* op = out + ((size_t)(b * PD + i + 1) * PD + (j + 1)) * CH;
    f16x4 s4;
    #pragma unroll
    for (int k = 0; k < 4; k++) s4[k] = (_Float16)acc4[k];
    *(f16x4*)(op + r * 4) = s4;
    f16x2 s2;
    s2[0] = (_Float16)acc2[0];
    s2[1] = (_Float16)acc2[1];
    *(f16x2*)(op + 64 + r * 2) = s2;
}

// ---------------------------------------------------------------------------
// Conv 3x3 + BN + ReLU, f16 MFMA implicit GEMM. (unchanged, round-11 proven:
// 512 thr, 8 waves, 10x34 pixel-major LDS, depth-1 SAB/SBA, grid 800 + XCD
// swizzle, FRAGMENT-ORDER weights)
// ---------------------------------------------------------------------------
#define LOAD_FRAGS(WF, PF, STEP) do {                                              \
    constexpr int _tap = (STEP) / 3, _kc = (STEP) % 3;                             \
    constexpr int _r = _tap / 3, _s = _tap % 3;                                    \
    _Pragma("unroll")                                                              \
    for (int ot = 0; ot < 3; ++ot)                                                 \
        WF[ot] = *(const f16x8*)(wtb + _tap * 9216 + _kc * 3072 + ot * 512);       \
    _Pragma("unroll")                                                              \
    for (int pt = 0; pt < 4; ++pt)                                                 \
        PF[pt] = *(const f16x8*)(&sA[((2 * rp + (pt >> 1) + _r) * 34               \
                         + (pt & 1) * 16 + _s + n) * 104 + _kc * 32 + q * 8]);     \
} while (0)

#define DO_MFMA(WF, PF) do {                                                       \
    _Pragma("unroll")                                                              \
    for (int ot = 0; ot < 3; ++ot)                                                 \
        _Pragma("unroll")                                                          \
        for (int pt = 0; pt < 4; ++pt)                                             \
            acc[ot][pt] = __builtin_amdgcn_mfma_f32_16x16x32_f16(                  \
                              WF[ot], PF[pt], acc[ot][pt], 0, 0, 0);               \
} while (0)

#define SAB(S) LOAD_FRAGS(wfb, pfb, (S) + 1); DO_MFMA(wfa, pfa);
#define SBA(S) LOAD_FRAGS(wfa, pfa, (S) + 1); DO_MFMA(wfb, pfb);

template<int MODE>
__global__ __launch_bounds__(512, 4) void k_conv_mfma(
        const _Float16* __restrict__ in, const _Float16* __restrict__ wt,
        const float* __restrict__ bng, const float* __restrict__ bnb,
        const float* __restrict__ bnm, const float* __restrict__ bnv,
        void* __restrict__ outv) {
    __shared__ _Float16 sA[10 * 34 * 104];   // 70,720 B -> 2 blocks/CU
    const int tid = threadIdx.x;
    const int w = tid >> 6, lane = tid & 63, q = lane >> 4, n = lane & 15;
    const int rp = w >> 1;          // row-pair 0..3
    const int och = w & 1;          // oc half 0..1

    // bijective XCD swizzle: 800 % 8 == 0
    const int bid = blockIdx.x;
    const int swz = (bid & 7) * 100 + (bid >> 3);
    const int b = swz / 400;
    const int r2 = swz - b * 400;
    const int ty = r2 / 10, tx = r2 - ty * 10;
    const int x0 = tx * 32, y0 = ty * 8;

    const _Float16* inb = in + (size_t)b * PPIX * CH;

    for (int idx = tid; idx < 10 * 34 * 12; idx += 512) {
        int pix = idx / 12, c8 = idx - pix * 12;
        int rr = pix / 34, cc = pix - rr * 34;
        *(f16x8*)(&sA[pix * 104 + c8 * 8]) =
            *(const f16x8*)(inb + ((size_t)(y0 + rr) * PD + (x0 + cc)) * CH + c8 * 8);
    }
    __syncthreads();

    f32x4 acc[3][4];
    #pragma unroll
    for (int ot = 0; ot < 3; ot++)
        #pragma unroll
        for (int pt = 0; pt < 4; pt++) acc[ot][pt] = (f32x4){0.f, 0.f, 0.f, 0.f};

    // fragment-order weights: + och half, + per-lane 16B slot
    const _Float16* wtb = wt + och * 1536 + lane * 8;

    f16x8 wfa[3], wfb[3], pfa[4], pfb[4];
    LOAD_FRAGS(wfa, pfa, 0);
    SAB(0)  SBA(1)  SAB(2)  SBA(3)  SAB(4)  SBA(5)  SAB(6)  SBA(7)
    SAB(8)  SBA(9)  SAB(10) SBA(11) SAB(12) SBA(13) SAB(14) SBA(15)
    SAB(16) SBA(17) SAB(18) SBA(19) SAB(20) SBA(21) SAB(22) SBA(23)
    SAB(24) SBA(25)
    DO_MFMA(wfa, pfa);   // step 26 (loaded by SBA(25))

    float scv[3][4], shv[3][4];
    #pragma unroll
    for (int ot = 0; ot < 3; ot++)
        #pragma unroll
        for (int rg = 0; rg < 4; rg++) {
            int oc = och * 48 + ot * 16 + q * 4 + rg;
            scv[ot][rg] = bng[oc] * rsqrtf(bnv[oc] + 1e-3f);
            shv[ot][rg] = fmaf(-bnm[oc], scv[ot][rg], bnb[oc]);
        }

    if (MODE == 0) {
        _Float16* outb = (_Float16*)outv + (size_t)b * PPIX * CH;
        #pragma unroll
        for (int pt = 0; pt < 4; pt++) {
            const int orow = y0 + 2 * rp + (pt >> 1) + 1;
            const int ocol = x0 + (pt & 1) * 16 + n + 1;
            _Float16* op = outb + ((size_t)orow * PD + ocol) * CH + och * 48 + q * 4;
            #pragma unroll
            for (int ot = 0; ot < 3; ot++) {
                f16x4 pv;
                #pragma unroll
                for (int rg = 0; rg < 4; rg++)
                    pv[rg] = (_Float16)fmaxf(fmaf(acc[ot][pt][rg], scv[ot][rg], shv[ot][rg]), 0.f);
                *(f16x4*)(op + ot * 16) = pv;
            }
        }
    } else {
        float* outb = (float*)outv + (size_t)b * CH * NCELL;
        #pragma unroll
        for (int pt = 0; pt < 4; pt++) {
            const int prow = y0 + 2 * rp + (pt >> 1);
            const int pcol = x0 + (pt & 1) * 16 + n;
            #pragma unroll
            for (int ot = 0; ot < 3; ot++)
                #pragma unroll
                for (int rg = 0; rg < 4; rg++) {
                    int oc = och * 48 + ot * 16 + q * 4 + rg;
                    outb[(size_t)oc * NCELL + prow * BEV + pcol] =
                        fmaxf(fmaf(acc[ot][pt][rg], scv[ot][rg], shv[ot][rg]), 0.f);
                }
        }
    }
}

// ---------------------------------------------------------------------------
extern "C" void kernel_launch(void* const* d_in, const int* in_sizes, int n_in,
                              void* d_out, int out_size, void* d_ws, size_t ws_size,
                              hipStream_t stream) {
    const float* feat = (const float*)d_in[0];
    const float* l2i  = (const float*)d_in[1];
    const float* he   = (const float*)d_in[2];
    const float* dw1  = (const float*)d_in[3];
    const float* db1  = (const float*)d_in[4];
    const float* dw2  = (const float*)d_in[5];
    const float* db2  = (const float*)d_in[6];
    const float* sw1  = (const float*)d_in[7];
    const float* sb1  = (const float*)d_in[8];
    const float* sw2  = (const float*)d_in[9];
    const float* sb2  = (const float*)d_in[10];
    const float* c1w  = (const float*)d_in[11];
    const float* bn1g = (const float*)d_in[12];
    const float* bn1b = (const float*)d_in[13];
    const float* bn1m = (const float*)d_in[14];
    const float* bn1v = (const float*)d_in[15];
    const float* c2w  = (const float*)d_in[16];
    const float* bn2g = (const float*)d_in[17];
    const float* bn2b = (const float*)d_in[18];
    const float* bn2m = (const float*)d_in[19];
    const float* bn2v = (const float*)d_in[20];

    float* ws = (float*)d_ws;
    _Float16*  bufB   = (_Float16*)(ws + OFF_BUFB);
    _Float16*  featS  = (_Float16*)(ws + OFF_FS);   // aliases bufB (dead before conv1)
    _Float16*  featH  = (_Float16*)(ws + OFF_FH);   // aliases bufB (dead before conv1)
    _Float16*  wtp    = (_Float16*)(ws + OFF_WT);
    float*     hW     = ws + OFF_HW;
    float*     baseT  = ws + OFF_BASE;
    float*     wD     = ws + OFF_WD;
    float*     flagp  = ws + OFF_FLAG;
    _Float16*  sw1p   = (_Float16*)(ws + OFF_SW1H);
    _Float16*  bufA   = (_Float16*)(ws + OFF_BUFA);
    _Float16*  wt1    = wtp;
    _Float16*  wt2    = wtp + 82944;

    hipLaunchKernelGGL(k_setup, dim3(700), dim3(256), 0, stream,
                       dw2, sw1, db2, he, sb1, db1, c1w, c2w,
                       hW, baseT, flagp, sw1p, wtp, bufA);
    hipLaunchKernelGGL(k_setup2, dim3(1), dim3(64), 0, stream, dw1, hW, wD);
    hipLaunchKernelGGL(k_tr, dim3(FPIX / 64, 2), dim3(256), 0, stream, feat, featH);
    hipLaunchKernelGGL(k_fs, dim3(704), dim3(512), 0, stream, featH, sw1p, featS);
    hipLaunchKernelGGL(k_lift, dim3(NCELL / 16, 2), dim3(256), 0, stream,
                       featS, featH, l2i, dw1, db1, sw2, sb2, hW, baseT, wD, flagp, bufA);
    // bufB borders only after k_lift (featS/featH alias bufB)
    hipLaunchKernelGGL(k_border, dim3(11), dim3(256), 0, stream, bufB);
    hipLaunchKernelGGL((k_conv_mfma<0>), dim3(800), dim3(512), 0, stream,
                       bufA, wt1, bn1g, bn1b, bn1m, bn1v, (void*)bufB);
    hipLaunchKernelGGL((k_conv_mfma<1>), dim3(800), dim3(512), 0, stream,
                       bufB, wt2, bn2g, bn2b, bn2m, bn2v, d_out);
}

// Round 13
// 291.085 us; speedup vs baseline: 1.1678x; 1.0583x over previous
//
#include <hip/hip_runtime.h>
#include <math.h>

typedef _Float16 f16x8 __attribute__((ext_vector_type(8)));
typedef _Float16 f16x4 __attribute__((ext_vector_type(4)));
typedef _Float16 f16x2 __attribute__((ext_vector_type(2)));
typedef float    f32x4 __attribute__((ext_vector_type(4)));

#define FEAT_H 128
#define FEAT_W 352
#define FPIX   (FEAT_H * FEAT_W)   // 45056
#define BEV    320
#define NCELL  (BEV * BEV)         // 102400
#define CH     96
#define PD     322                 // padded spatial dim
#define PPIX   (PD * PD)           // 103684

// ---- workspace layout (float offsets) ----
#define N_PADF    (2 * PPIX * CH / 2)            // 9,953,664 floats
#define OFF_BUFB  0
#define OFF_FS    0                              // featS16: 2*45056*64 f16
#define OFF_FH    2883584                        // featH16: 2*45056*96 f16
#define OFF_WT    (N_PADF)                       // f16 2*9*96*96 = 82,944 floats
#define OFF_HW    (OFF_WT + 82944)               // 64*64 fp32
#define OFF_BASE  (OFF_HW + 4096)                // baseT 192 | wD 64 | flag 1
#define OFF_WD    (OFF_BASE + 192)
#define OFF_FLAG  (OFF_BASE + 256)
#define OFF_SW1H  (OFF_BASE + 512)               // sw1 fragment-order f16: 6144 f16 = 3072 floats
#define OFF_BUFA  (OFF_SW1H + 3072)              // f16 padded conv1 input

// ---------------------------------------------------------------------------
// k_setup:
//   blocks 0..15   -> hW (1 output/thread, parallel)
//   block  16      -> baseT (192 outputs) + flag
//   blocks 17..40  -> sw1p: sw1 in MFMA B-FRAGMENT order [kc][nt][lane][8]
//   blocks 41..688 -> conv weight prep (fragment order)
//   blocks 689..699-> bufA border zero
// wD (depends on hW) in k_setup2 (stream order = dependency).
// ---------------------------------------------------------------------------
__global__ void k_setup(const float* __restrict__ dw2, const float* __restrict__ sw1,
                        const float* __restrict__ db2, const float* __restrict__ he,
                        const float* __restrict__ sb1, const float* __restrict__ db1,
                        const float* __restrict__ w1, const float* __restrict__ w2,
                        float* __restrict__ hW, float* __restrict__ baseT,
                        float* __restrict__ flagp, _Float16* __restrict__ sw1p,
                        _Float16* __restrict__ wt, _Float16* __restrict__ bufA) {
    const int bid = blockIdx.x;
    const int t = threadIdx.x;
    if (bid < 16) {
        const int idx = bid * 256 + t;              // 0..4095
        const int j = idx >> 6, k = idx & 63;
        float s = 0.f;
        for (int c = 0; c < CH; c++) s = fmaf(dw2[j * CH + c], sw1[c * 64 + k], s);
        hW[idx] = s;
    } else if (bid == 16) {
        if (t < 192) {
            const int h = t >> 6, k = t & 63;
            float s = sb1[k];
            for (int c = 0; c < CH; c++) s = fmaf(db2[c] + he[h * CH + c], sw1[c * 64 + k], s);
            baseT[t] = s;
        } else if (t == 192) {
            float mx = 0.f;
            for (int j = 0; j < 64; j++) mx = fmaxf(mx, fabsf(db1[j]));
            flagp[0] = (mx == 0.f) ? 1.f : 0.f;
        }
    } else if (bid <= 40) {
        const int idx = (bid - 17) * 256 + t;       // 0..6143
        const int e  = idx & 7;
        const int l  = (idx >> 3) & 63;
        const int nt = (idx >> 9) & 3;
        const int kc = idx >> 11;                   // 0..2
        const int q = l >> 4, n = l & 15;
        sw1p[idx] = (_Float16)sw1[(kc * 32 + q * 8 + e) * 64 + nt * 16 + n];
    } else if (bid <= 688) {
        int idx = (bid - 41) * 256 + t;             // 0 .. 165887
        int cv = idx / 82944; int r = idx - cv * 82944;
        // fragment-order decompose: tap, kc, och, ot, lane, e
        int tap = r / 9216;   int r2 = r - tap * 9216;     // 9216 = 3*2*3*512
        int kc  = r2 / 3072;  int r3 = r2 - kc * 3072;
        int och = r3 / 1536;  int r4 = r3 - och * 1536;
        int ot  = r4 / 512;   int r5 = r4 - ot * 512;
        int l   = r5 >> 3;    int e  = r5 & 7;
        int oc  = och * 48 + ot * 16 + (l & 15);
        int ic  = kc * 32 + (l >> 4) * 8 + e;
        const float* src = cv ? w2 : w1;
        wt[idx] = (_Float16)src[(oc * 96 + ic) * 9 + tap];
    } else {
        int idx = (bid - 689) * 256 + t;            // 0 .. 2815 (need 2568)
        if (idx >= 2568) return;
        int img = idx / 1284; int p = idx - img * 1284;
        int row, col;
        if (p < 322)      { row = 0;           col = p; }
        else if (p < 644) { row = 321;         col = p - 322; }
        else if (p < 964) { row = p - 644 + 1; col = 0; }
        else              { row = p - 964 + 1; col = 321; }
        _Float16* q = bufA + ((size_t)(img * PD + row) * PD + col) * CH;
        f16x8 z = {};
        #pragma unroll
        for (int c8 = 0; c8 < 12; ++c8) *(f16x8*)(q + c8 * 8) = z;
    }
}

// ---------------------------------------------------------------------------
// k_setup2: wD[t] = sum_j relu-gated dw1[j] * hW[j][t]  (after k_setup).
// ---------------------------------------------------------------------------
__global__ __launch_bounds__(64) void k_setup2(const float* __restrict__ dw1,
                                               const float* __restrict__ hW,
                                               float* __restrict__ wD) {
    const int t = threadIdx.x;
    float s = 0.f;
    for (int j = 0; j < 64; j++) {
        float w = dw1[j];
        if (w > 0.f) s = fmaf(w, hW[j * 64 + t], s);
    }
    wD[t] = s;
}

// ---------------------------------------------------------------------------
// Zero the 1-pixel border of a padded f16 HWC buffer [2][322][322][96]
// ---------------------------------------------------------------------------
__global__ void k_border(_Float16* __restrict__ buf) {
    int idx = blockIdx.x * 256 + threadIdx.x;       // 2*1284 = 2568 border pixels
    if (idx >= 2568) return;
    int img = idx / 1284; int p = idx - img * 1284;
    int row, col;
    if (p < 322)      { row = 0;           col = p; }
    else if (p < 644) { row = 321;         col = p - 322; }
    else if (p < 964) { row = p - 644 + 1; col = 0; }
    else              { row = p - 964 + 1; col = 321; }
    _Float16* q = buf + ((size_t)(img * PD + row) * PD + col) * CH;
    f16x8 z = {};
    #pragma unroll
    for (int c8 = 0; c8 < 12; ++c8) *(f16x8*)(q + c8 * 8) = z;
}

// ---------------------------------------------------------------------------
// k_tr: pure streaming CHW->HWC transpose (feat f32 -> featH f16). (proven)
// ---------------------------------------------------------------------------
__global__ __launch_bounds__(256) void k_tr(const float* __restrict__ feat,
                                            _Float16* __restrict__ featH) {
    const int tid = threadIdx.x;
    const int kq = tid >> 6;                // channel quarter 0..3
    const int t = tid & 63;                 // pixel lane
    const int pb = blockIdx.x * 64;
    const int b = blockIdx.y;
    const float* fp = feat + (size_t)b * CH * FPIX + (size_t)(kq * 24) * FPIX + pb + t;
    _Float16* opH = featH + ((size_t)b * FPIX + pb + t) * 96 + kq * 24;

    float x[24];
    #pragma unroll
    for (int c = 0; c < 24; c++) x[c] = fp[(size_t)c * FPIX];
    #pragma unroll
    for (int c8 = 0; c8 < 3; c8++) {
        f16x8 v;
        #pragma unroll
        for (int e = 0; e < 8; e++) v[e] = (_Float16)x[c8 * 8 + e];
        *(f16x8*)(opH + c8 * 8) = v;
    }
}

// ---------------------------------------------------------------------------
// k_fs: featS = featH @ sw1 as an f16 MFMA GEMM. (proven)
// ---------------------------------------------------------------------------
__global__ __launch_bounds__(512, 2) void k_fs(const _Float16* __restrict__ featH,
                                               const _Float16* __restrict__ sw1p,
                                               _Float16* __restrict__ featS) {
    const int tid = threadIdx.x;
    const int wid = tid >> 6, lane = tid & 63;
    const int q = lane >> 4, n = lane & 15;
    const int mt = blockIdx.x * 8 + wid;    // 0..5631

    f16x8 bf[3][4];
    #pragma unroll
    for (int kc = 0; kc < 3; kc++)
        #pragma unroll
        for (int nt = 0; nt < 4; nt++)
            bf[kc][nt] = *(const f16x8*)(sw1p + ((kc * 4 + nt) * 64 + lane) * 8);

    f16x8 a[3];
    const _Float16* ar = featH + (size_t)(mt * 16 + n) * 96 + q * 8;
    #pragma unroll
    for (int kc = 0; kc < 3; kc++) a[kc] = *(const f16x8*)(ar + kc * 32);

    f32x4 acc[4];
    #pragma unroll
    for (int nt = 0; nt < 4; nt++) acc[nt] = (f32x4){0.f, 0.f, 0.f, 0.f};
    #pragma unroll
    for (int kc = 0; kc < 3; kc++)
        #pragma unroll
        for (int nt = 0; nt < 4; nt++)
            acc[nt] = __builtin_amdgcn_mfma_f32_16x16x32_f16(a[kc], bf[kc][nt], acc[nt], 0, 0, 0);

    _Float16* os = featS + (size_t)(mt * 16 + q * 4) * 64 + n;
    #pragma unroll
    for (int nt = 0; nt < 4; nt++)
        #pragma unroll
        for (int rg = 0; rg < 4; rg++)
            os[(size_t)rg * 64 + nt * 16] = (_Float16)acc[nt][rg];
}

// ---------------------------------------------------------------------------
// k_lift (round 19): per-cell geometry de-duplication.
// Round-12 PMC: VALUBusy 74.9% — VALU-bound; ~16x redundant per-group
// geometry (3 heights x ~70 ops incl. 2 divides + log1pf) was ~1/3 of VALU.
// Phase 1: threads 0..47 compute (cell,height) geometry once -> LDS (~1.9KB).
// Phase 2: groups read broadcast LDS; featS dot/butterfly/softmax/gather
// unchanged.
// ---------------------------------------------------------------------------
__global__ __launch_bounds__(256, 4) void k_lift(const _Float16* __restrict__ featS,
                                                 const _Float16* __restrict__ featH,
                                                 const float* __restrict__ l2i,
                                                 const float* __restrict__ dw1,
                                                 const float* __restrict__ db1,
                                                 const float* __restrict__ sw2,
                                                 const float* __restrict__ sb2,
                                                 const float* __restrict__ hW,
                                                 const float* __restrict__ baseT,
                                                 const float* __restrict__ wD,
                                                 const float* __restrict__ flagp,
                                                 _Float16* __restrict__ out) {
    __shared__ int   s_ti[16][3][4];
    __shared__ float s_tw[16][3][4];
    __shared__ float s_dl[16][3];
    __shared__ int   s_vld[16][3];

    const int tid = threadIdx.x;
    const int g = tid >> 4;                 // group (cell) within block: 0..15
    const int r = tid & 15;                 // lane within group: 0..15
    const int b = blockIdx.y;

    // ---- phase 1: 48 threads compute geometry for 16 cells x 3 heights ----
    if (tid < 48) {
        const int c = tid / 3;
        const int h = tid - 3 * c;
        const int cell = blockIdx.x * 16 + c;
        const int i = cell / BEV, j = cell % BEV;
        const float px = ((j + 0.5f) / 320.0f) * 102.4f - 51.2f;
        const float py = ((i + 0.5f) / 320.0f) * 102.4f - 51.2f;
        const float* M = l2i + b * 16;
        const float z = (float)h;
        const float p0 = M[3]  + M[0] * px + M[1] * py + M[2]  * z;
        const float p1 = M[7]  + M[4] * px + M[5] * py + M[6]  * z;
        const float dep = M[11] + M[8] * px + M[9] * py + M[10] * z;
        const float dv = fmaxf(dep, 1e-5f);
        const float u = p0 / dv, v = p1 / dv;
        const float gx = (u / 351.0f) * 2.0f - 1.0f;
        const float gy = (v / 127.0f) * 2.0f - 1.0f;
        const bool valid = (dep > 1e-3f) && (fabsf(gx) <= 1.0f) && (fabsf(gy) <= 1.0f);
        s_vld[c][h] = valid ? 1 : 0;
        if (valid) {
            float xs = (gx + 1.0f) * 0.5f * 351.0f;
            float ys = (gy + 1.0f) * 0.5f * 127.0f;
            float xf = floorf(xs), yf = floorf(ys);
            int x0 = (int)xf, y0 = (int)yf;
            float wx = xs - xf, wy = ys - yf;
            int x1 = (x0 < FEAT_W - 1) ? x0 + 1 : x0;
            int y1 = (y0 < FEAT_H - 1) ? y0 + 1 : y0;
            s_ti[c][h][0] = y0 * FEAT_W + x0;  s_ti[c][h][1] = y0 * FEAT_W + x1;
            s_ti[c][h][2] = y1 * FEAT_W + x0;  s_ti[c][h][3] = y1 * FEAT_W + x1;
            s_tw[c][h][0] = (1.f - wx) * (1.f - wy);
            s_tw[c][h][1] = wx * (1.f - wy);
            s_tw[c][h][2] = (1.f - wx) * wy;
            s_tw[c][h][3] = wx * wy;
            s_dl[c][h] = log1pf(fmaxf(dep, 1e-3f));
        }
    }
    __syncthreads();

    const _Float16* fSb = featS + (size_t)b * FPIX * 64;
    const _Float16* fHb = featH + (size_t)b * FPIX * 96;

    // per-lane channel slices of the small tables
    const f32x4 wdv = *(const f32x4*)(wD + r * 4);
    const f32x4 sv  = *(const f32x4*)(sw2 + r * 4);
    const float sb2v = sb2[0];
    const bool fast = (flagp[0] != 0.f);

    int   ti[3][4];
    float tw[3][4];
    float logit[3];

    #pragma unroll
    for (int h = 0; h < 3; h++) {
        logit[h] = -INFINITY;
        ti[h][0] = ti[h][1] = ti[h][2] = ti[h][3] = 0;
        tw[h][0] = tw[h][1] = tw[h][2] = tw[h][3] = 0.f;
        if (!s_vld[g][h]) continue;                 // group-uniform branch
        #pragma unroll
        for (int k = 0; k < 4; k++) { ti[h][k] = s_ti[g][h][k]; tw[h][k] = s_tw[g][h][k]; }
        const float tw0 = tw[h][0], tw1 = tw[h][1], tw2 = tw[h][2], tw3 = tw[h][3];
        const float dl = s_dl[g][h];

        // coalesced featS taps: 16 lanes x 8B = one 128B line per tap
        f16x4 t0 = *(const f16x4*)(fSb + (size_t)ti[h][0] * 64 + r * 4);
        f16x4 t1 = *(const f16x4*)(fSb + (size_t)ti[h][1] * 64 + r * 4);
        f16x4 t2 = *(const f16x4*)(fSb + (size_t)ti[h][2] * 64 + r * 4);
        f16x4 t3 = *(const f16x4*)(fSb + (size_t)ti[h][3] * 64 + r * 4);
        const f32x4 bs = *(const f32x4*)(baseT + h * 64 + r * 4);

        float hid[4];
        if (fast) {
            #pragma unroll
            for (int k = 0; k < 4; k++) hid[k] = fmaf(dl, wdv[k], bs[k]);
        } else {
            #pragma unroll
            for (int k = 0; k < 4; k++) hid[k] = bs[k];
            for (int jj = 0; jj < 64; jj++) {
                float hd = fmaxf(fmaf(dl, dw1[jj], db1[jj]), 0.f);
                const f32x4 hv = *(const f32x4*)(hW + jj * 64 + r * 4);
                #pragma unroll
                for (int k = 0; k < 4; k++) hid[k] = fmaf(hd, hv[k], hid[k]);
            }
        }
        float part = 0.f;
        #pragma unroll
        for (int k = 0; k < 4; k++) {
            float s = fmaf(tw0, (float)t0[k], fmaf(tw1, (float)t1[k],
                      fmaf(tw2, (float)t2[k], tw3 * (float)t3[k])));
            part = fmaf(fmaxf(hid[k] + s, 0.f), sv[k], part);
        }
        // butterfly reduce across the 16-lane group
        #pragma unroll
        for (int m = 1; m < 16; m <<= 1) part += __shfl_xor(part, m, 16);
        logit[h] = part + sb2v;
    }

    const float mx = fmaxf(logit[0], fmaxf(logit[1], logit[2]));
    float wh[3] = {0.f, 0.f, 0.f};
    if (mx > -INFINITY) {
        float e0 = (logit[0] > -INFINITY) ? expf(logit[0] - mx) : 0.f;
        float e1 = (logit[1] > -INFINITY) ? expf(logit[1] - mx) : 0.f;
        float e2 = (logit[2] > -INFINITY) ? expf(logit[2] - mx) : 0.f;
        const float inv = 1.0f / (e0 + e1 + e2);
        wh[0] = e0 * inv; wh[1] = e1 * inv; wh[2] = e2 * inv;
    }

    // fused 96-ch weighted gather: lane r owns ch [4r..4r+3] and [64+2r..64+2r+1]
    float acc4[4] = {0.f, 0.f, 0.f, 0.f};
    float acc2[2] = {0.f, 0.f};
    #pragma unroll
    for (int h = 0; h < 3; h++) {
        if (wh[h] > 0.f) {                          // group-uniform branch
            #pragma unroll
            for (int t = 0; t < 4; t++) {
                const float c = wh[h] * tw[h][t];
                const _Float16* gp = fHb + (size_t)ti[h][t] * 96;
                f16x4 v4 = *(const f16x4*)(gp + r * 4);
                f16x2 v2 = *(const f16x2*)(gp + 64 + r * 2);
                #pragma unroll
                for (int k = 0; k < 4; k++) acc4[k] = fmaf(c, (float)v4[k], acc4[k]);
                acc2[0] = fmaf(c, (float)v2[0], acc2[0]);
                acc2[1] = fmaf(c, (float)v2[1], acc2[1]);
            }
        }
    }
    const int cell = blockIdx.x * 16 + g;
    const int i = cell / BEV, j = cell % BEV;
    _Float16* op = out + ((size_t)(b * PD + i + 1) * PD + (j + 1)) * CH;
    f16x4 s4;
    #pragma unroll
    for (int k = 0; k < 4; k++) s4[k] = (_Float16)acc4[k];
    *(f16x4*)(op + r * 4) = s4;
    f16x2 s2;
    s2[0] = (_Float16)acc2[0];
    s2[1] = (_Float16)acc2[1];
    *(f16x2*)(op + 64 + r * 2) = s2;
}

// ---------------------------------------------------------------------------
// Conv 3x3 + BN + ReLU, f16 MFMA implicit GEMM. (unchanged, proven:
// 512 thr, 8 waves, 10x34 pixel-major LDS, depth-1 SAB/SBA, grid 800 + XCD
// swizzle, FRAGMENT-ORDER weights)
// ---------------------------------------------------------------------------
#define LOAD_FRAGS(WF, PF, STEP) do {                                              \
    constexpr int _tap = (STEP) / 3, _kc = (STEP) % 3;                             \
    constexpr int _r = _tap / 3, _s = _tap % 3;                                    \
    _Pragma("unroll")                                                              \
    for (int ot = 0; ot < 3; ++ot)                                                 \
        WF[ot] = *(const f16x8*)(wtb + _tap * 9216 + _kc * 3072 + ot * 512);       \
    _Pragma("unroll")                                                              \
    for (int pt = 0; pt < 4; ++pt)                                                 \
        PF[pt] = *(const f16x8*)(&sA[((2 * rp + (pt >> 1) + _r) * 34               \
                         + (pt & 1) * 16 + _s + n) * 104 + _kc * 32 + q * 8]);     \
} while (0)

#define DO_MFMA(WF, PF) do {                                                       \
    _Pragma("unroll")                                                              \
    for (int ot = 0; ot < 3; ++ot)                                                 \
        _Pragma("unroll")                                                          \
        for (int pt = 0; pt < 4; ++pt)                                             \
            acc[ot][pt] = __builtin_amdgcn_mfma_f32_16x16x32_f16(                  \
                              WF[ot], PF[pt], acc[ot][pt], 0, 0, 0);               \
} while (0)

#define SAB(S) LOAD_FRAGS(wfb, pfb, (S) + 1); DO_MFMA(wfa, pfa);
#define SBA(S) LOAD_FRAGS(wfa, pfa, (S) + 1); DO_MFMA(wfb, pfb);

template<int MODE>
__global__ __launch_bounds__(512, 4) void k_conv_mfma(
        const _Float16* __restrict__ in, const _Float16* __restrict__ wt,
        const float* __restrict__ bng, const float* __restrict__ bnb,
        const float* __restrict__ bnm, const float* __restrict__ bnv,
        void* __restrict__ outv) {
    __shared__ _Float16 sA[10 * 34 * 104];   // 70,720 B -> 2 blocks/CU
    const int tid = threadIdx.x;
    const int w = tid >> 6, lane = tid & 63, q = lane >> 4, n = lane & 15;
    const int rp = w >> 1;          // row-pair 0..3
    const int och = w & 1;          // oc half 0..1

    // bijective XCD swizzle: 800 % 8 == 0
    const int bid = blockIdx.x;
    const int swz = (bid & 7) * 100 + (bid >> 3);
    const int b = swz / 400;
    const int r2 = swz - b * 400;
    const int ty = r2 / 10, tx = r2 - ty * 10;
    const int x0 = tx * 32, y0 = ty * 8;

    const _Float16* inb = in + (size_t)b * PPIX * CH;

    for (int idx = tid; idx < 10 * 34 * 12; idx += 512) {
        int pix = idx / 12, c8 = idx - pix * 12;
        int rr = pix / 34, cc = pix - rr * 34;
        *(f16x8*)(&sA[pix * 104 + c8 * 8]) =
            *(const f16x8*)(inb + ((size_t)(y0 + rr) * PD + (x0 + cc)) * CH + c8 * 8);
    }
    __syncthreads();

    f32x4 acc[3][4];
    #pragma unroll
    for (int ot = 0; ot < 3; ot++)
        #pragma unroll
        for (int pt = 0; pt < 4; pt++) acc[ot][pt] = (f32x4){0.f, 0.f, 0.f, 0.f};

    // fragment-order weights: + och half, + per-lane 16B slot
    const _Float16* wtb = wt + och * 1536 + lane * 8;

    f16x8 wfa[3], wfb[3], pfa[4], pfb[4];
    LOAD_FRAGS(wfa, pfa, 0);
    SAB(0)  SBA(1)  SAB(2)  SBA(3)  SAB(4)  SBA(5)  SAB(6)  SBA(7)
    SAB(8)  SBA(9)  SAB(10) SBA(11) SAB(12) SBA(13) SAB(14) SBA(15)
    SAB(16) SBA(17) SAB(18) SBA(19) SAB(20) SBA(21) SAB(22) SBA(23)
    SAB(24) SBA(25)
    DO_MFMA(wfa, pfa);   // step 26 (loaded by SBA(25))

    float scv[3][4], shv[3][4];
    #pragma unroll
    for (int ot = 0; ot < 3; ot++)
        #pragma unroll
        for (int rg = 0; rg < 4; rg++) {
            int oc = och * 48 + ot * 16 + q * 4 + rg;
            scv[ot][rg] = bng[oc] * rsqrtf(bnv[oc] + 1e-3f);
            shv[ot][rg] = fmaf(-bnm[oc], scv[ot][rg], bnb[oc]);
        }

    if (MODE == 0) {
        _Float16* outb = (_Float16*)outv + (size_t)b * PPIX * CH;
        #pragma unroll
        for (int pt = 0; pt < 4; pt++) {
            const int orow = y0 + 2 * rp + (pt >> 1) + 1;
            const int ocol = x0 + (pt & 1) * 16 + n + 1;
            _Float16* op = outb + ((size_t)orow * PD + ocol) * CH + och * 48 + q * 4;
            #pragma unroll
            for (int ot = 0; ot < 3; ot++) {
                f16x4 pv;
                #pragma unroll
                for (int rg = 0; rg < 4; rg++)
                    pv[rg] = (_Float16)fmaxf(fmaf(acc[ot][pt][rg], scv[ot][rg], shv[ot][rg]), 0.f);
                *(f16x4*)(op + ot * 16) = pv;
            }
        }
    } else {
        float* outb = (float*)outv + (size_t)b * CH * NCELL;
        #pragma unroll
        for (int pt = 0; pt < 4; pt++) {
            const int prow = y0 + 2 * rp + (pt >> 1);
            const int pcol = x0 + (pt & 1) * 16 + n;
            #pragma unroll
            for (int ot = 0; ot < 3; ot++)
                #pragma unroll
                for (int rg = 0; rg < 4; rg++) {
                    int oc = och * 48 + ot * 16 + q * 4 + rg;
                    outb[(size_t)oc * NCELL + prow * BEV + pcol] =
                        fmaxf(fmaf(acc[ot][pt][rg], scv[ot][rg], shv[ot][rg]), 0.f);
                }
        }
    }
}

// ---------------------------------------------------------------------------
extern "C" void kernel_launch(void* const* d_in, const int* in_sizes, int n_in,
                              void* d_out, int out_size, void* d_ws, size_t ws_size,
                              hipStream_t stream) {
    const float* feat = (const float*)d_in[0];
    const float* l2i  = (const float*)d_in[1];
    const float* he   = (const float*)d_in[2];
    const float* dw1  = (const float*)d_in[3];
    const float* db1  = (const float*)d_in[4];
    const float* dw2  = (const float*)d_in[5];
    const float* db2  = (const float*)d_in[6];
    const float* sw1  = (const float*)d_in[7];
    const float* sb1  = (const float*)d_in[8];
    const float* sw2  = (const float*)d_in[9];
    const float* sb2  = (const float*)d_in[10];
    const float* c1w  = (const float*)d_in[11];
    const float* bn1g = (const float*)d_in[12];
    const float* bn1b = (const float*)d_in[13];
    const float* bn1m = (const float*)d_in[14];
    const float* bn1v = (const float*)d_in[15];
    const float* c2w  = (const float*)d_in[16];
    const float* bn2g = (const float*)d_in[17];
    const float* bn2b = (const float*)d_in[18];
    const float* bn2m = (const float*)d_in[19];
    const float* bn2v = (const float*)d_in[20];

    float* ws = (float*)d_ws;
    _Float16*  bufB   = (_Float16*)(ws + OFF_BUFB);
    _Float16*  featS  = (_Float16*)(ws + OFF_FS);   // aliases bufB (dead before conv1)
    _Float16*  featH  = (_Float16*)(ws + OFF_FH);   // aliases bufB (dead before conv1)
    _Float16*  wtp    = (_Float16*)(ws + OFF_WT);
    float*     hW     = ws + OFF_HW;
    float*     baseT  = ws + OFF_BASE;
    float*     wD     = ws + OFF_WD;
    float*     flagp  = ws + OFF_FLAG;
    _Float16*  sw1p   = (_Float16*)(ws + OFF_SW1H);
    _Float16*  bufA   = (_Float16*)(ws + OFF_BUFA);
    _Float16*  wt1    = wtp;
    _Float16*  wt2    = wtp + 82944;

    hipLaunchKernelGGL(k_setup, dim3(700), dim3(256), 0, stream,
                       dw2, sw1, db2, he, sb1, db1, c1w, c2w,
                       hW, baseT, flagp, sw1p, wtp, bufA);
    hipLaunchKernelGGL(k_setup2, dim3(1), dim3(64), 0, stream, dw1, hW, wD);
    hipLaunchKernelGGL(k_tr, dim3(FPIX / 64, 2), dim3(256), 0, stream, feat, featH);
    hipLaunchKernelGGL(k_fs, dim3(704), dim3(512), 0, stream, featH, sw1p, featS);
    hipLaunchKernelGGL(k_lift, dim3(NCELL / 16, 2), dim3(256), 0, stream,
                       featS, featH, l2i, dw1, db1, sw2, sb2, hW, baseT, wD, flagp, bufA);
    // bufB borders only after k_lift (featS/featH alias bufB)
    hipLaunchKernelGGL(k_border, dim3(11), dim3(256), 0, stream, bufB);
    hipLaunchKernelGGL((k_conv_mfma<0>), dim3(800), dim3(512), 0, stream,
                       bufA, wt1, bn1g, bn1b, bn1m, bn1v, (void*)bufB);
    hipLaunchKernelGGL((k_conv_mfma<1>), dim3(800), dim3(512), 0, stream,
                       bufB, wt2, bn2g, bn2b, bn2m, bn2v, d_out);
}